// Round 1
// baseline (2380.368 us; speedup 1.0000x reference)
//
#include <hip/hip_runtime.h>

#define TT 60
#define DF 16
#define HH 128
#define CAP 1024

struct LayerArgs {
  const float* x; long xs;
  const float* h; long hs;     // h == nullptr -> first step (h=0, c=0)
  const float* Wih; const float* Whh;
  const float* bih; const float* bhh;
  const float* cin; float* cout;
  float* hout; long hos;
  int Kx; int active;
};

__device__ __forceinline__ float sigmoidf_(float x) {
  return 1.f / (1.f + __expf(-x));
}
__device__ __forceinline__ float tanhf_(float x) {
  x = fminf(fmaxf(x, -15.f), 15.f);
  float e = __expf(-2.f * x);
  return (1.f - e) / (1.f + e);
}

// Fused LSTM step: gates GEMM (A=[x_t | h_{t-1}], B=[Wih|Whh]^T) + pointwise.
// Grid: (ceil(N/64), 4, 2). z selects layer-0-step-t vs layer-1-step-(t-1).
// Gate columns interleaved: Bs col c -> gate q=c&3, d = d0 + (c>>2), so each
// thread owns all 4 gates of its d's entirely in registers for the epilogue.
__global__ __launch_bounds__(256) void lstm_step_dual(LayerArgs A0, LayerArgs A1, int N) {
  const LayerArgs La = (blockIdx.z == 0) ? A0 : A1;
  if (!La.active) return;
  const int tid = threadIdx.x;
  const int tx = tid & 15, ty = tid >> 4;
  const int row0 = blockIdx.x * 64;
  const int d0 = blockIdx.y * 32;

  __shared__ float As[16][68];    // pad 68: staging writes 2-way max
  __shared__ float Bs[16][128];
  __shared__ float bsum[128];

  if (tid < 128) {
    int q = tid & 3, dl = tid >> 2;
    bsum[tid] = La.bih[q*128 + d0 + dl] + La.bhh[q*128 + d0 + dl];
  }

  float acc[4][8];
  #pragma unroll
  for (int r = 0; r < 4; r++)
    #pragma unroll
    for (int j = 0; j < 8; j++) acc[r][j] = 0.f;

  const int an  = tid >> 2;          // A staging: row 0..63
  const int ak4 = (tid & 3) * 4;     // k sub-offset
  long arow = row0 + an; if (arow >= N) arow = N - 1;   // clamp (loads only)

  const int bc  = tid >> 1;          // B staging: col 0..127
  const int bk8 = (tid & 1) * 8;
  const int bg  = (bc & 3) * 128 + d0 + (bc >> 2);  // W row for this col

  const int Kx = La.Kx;
  const int Ktot = La.h ? Kx + 128 : Kx;    // Kx % 16 == 0, so tiles never straddle

  for (int K0 = 0; K0 < Ktot; K0 += 16) {
    float4 av, bv0, bv1;
    if (K0 < Kx) {
      av = *(const float4*)(La.x + arow * La.xs + K0 + ak4);
      const float* wp = La.Wih + (long)bg * Kx + K0 + bk8;
      bv0 = *(const float4*)wp; bv1 = *(const float4*)(wp + 4);
    } else {
      av = *(const float4*)(La.h + arow * La.hs + (K0 - Kx) + ak4);
      const float* wp = La.Whh + (long)bg * 128 + (K0 - Kx) + bk8;
      bv0 = *(const float4*)wp; bv1 = *(const float4*)(wp + 4);
    }
    __syncthreads();
    As[ak4+0][an] = av.x; As[ak4+1][an] = av.y; As[ak4+2][an] = av.z; As[ak4+3][an] = av.w;
    Bs[bk8+0][bc] = bv0.x; Bs[bk8+1][bc] = bv0.y; Bs[bk8+2][bc] = bv0.z; Bs[bk8+3][bc] = bv0.w;
    Bs[bk8+4][bc] = bv1.x; Bs[bk8+5][bc] = bv1.y; Bs[bk8+6][bc] = bv1.z; Bs[bk8+7][bc] = bv1.w;
    __syncthreads();
    #pragma unroll
    for (int k = 0; k < 16; k++) {
      const float4 a4 = *(const float4*)&As[k][ty * 4];
      const float4 b0 = *(const float4*)&Bs[k][tx * 4];
      const float4 b1 = *(const float4*)&Bs[k][64 + tx * 4];
      const float ar[4] = {a4.x, a4.y, a4.z, a4.w};
      const float br[8] = {b0.x, b0.y, b0.z, b0.w, b1.x, b1.y, b1.z, b1.w};
      #pragma unroll
      for (int r = 0; r < 4; r++)
        #pragma unroll
        for (int j = 0; j < 8; j++)
          acc[r][j] += ar[r] * br[j];
    }
  }

  #pragma unroll
  for (int r = 0; r < 4; r++) {
    long n = row0 + ty * 4 + r;
    if (n >= N) continue;
    #pragma unroll
    for (int half = 0; half < 2; half++) {
      int d = d0 + half * 16 + tx;
      float gi = acc[r][half*4+0] + bsum[half*64 + tx*4 + 0];
      float gf = acc[r][half*4+1] + bsum[half*64 + tx*4 + 1];
      float gg = acc[r][half*4+2] + bsum[half*64 + tx*4 + 2];
      float go = acc[r][half*4+3] + bsum[half*64 + tx*4 + 3];
      float i_ = sigmoidf_(gi), f_ = sigmoidf_(gf);
      float g_ = tanhf_(gg),    o_ = sigmoidf_(go);
      float cp = La.cin ? La.cin[n*128 + d] : 0.f;
      float cn = f_ * cp + i_ * g_;
      float hn = o_ * tanhf_(cn);
      La.cout[n*128 + d] = cn;
      La.hout[n*La.hos + d] = hn;
    }
  }
}

// u_src = W_t^T a[:H], u_dst = W_t^T a[H:], c_* = b_t . a-half -> uv[258]
__global__ void attn_prep(const float* __restrict__ Wt, const float* __restrict__ bt,
                          const float* __restrict__ a, float* __restrict__ uv) {
  int k = threadIdx.x;   // 128
  float us = 0.f, ud = 0.f;
  for (int j = 0; j < 128; j++) {
    float w = Wt[j*128 + k];
    us += a[j] * w;
    ud += a[128 + j] * w;
  }
  uv[k] = us; uv[128 + k] = ud;
  __shared__ float red[128];
  red[k] = bt[k] * a[k];
  __syncthreads();
  for (int st = 64; st; st >>= 1) { if (k < st) red[k] += red[k + st]; __syncthreads(); }
  if (k == 0) uv[256] = red[0];
  __syncthreads();
  red[k] = bt[k] * a[128 + k];
  __syncthreads();
  for (int st = 64; st; st >>= 1) { if (k < st) red[k] += red[k + st]; __syncthreads(); }
  if (k == 0) uv[257] = red[0];
}

// s_src[i] = hid[i].u_src + c_src ; s_dst likewise. One wave per row.
__global__ void attn_scores(const float* __restrict__ hid, const float* __restrict__ uv,
                            float* __restrict__ ssrc, float* __restrict__ sdst, int N) {
  int wave = threadIdx.x >> 6, lane = threadIdx.x & 63;
  int i = blockIdx.x * 4 + wave;
  if (i >= N) return;
  float h0 = hid[(long)i*128 + lane], h1 = hid[(long)i*128 + 64 + lane];
  float us = h0 * uv[lane]       + h1 * uv[64 + lane];
  float ud = h0 * uv[128 + lane] + h1 * uv[192 + lane];
  for (int off = 32; off; off >>= 1) { us += __shfl_down(us, off); ud += __shfl_down(ud, off); }
  if (lane == 0) { ssrc[i] = us + uv[256]; sdst[i] = ud + uv[257]; }
}

__global__ void colsum_part(const float* __restrict__ hid, float* __restrict__ part, int N) {
  int d = threadIdx.x, b = blockIdx.x;   // 32 x 128
  int per = (N + 31) / 32;
  int n0 = b * per, n1 = min(N, n0 + per);
  float s = 0.f;
  for (int n = n0; n < n1; n++) s += hid[(long)n*128 + d];
  part[b*128 + d] = s;
}
__global__ void colsum_fold(const float* __restrict__ part, float* __restrict__ csum) {
  int d = threadIdx.x;
  float s = 0.f;
  for (int b = 0; b < 32; b++) s += part[b*128 + d];
  csum[d] = s;
}

// Per-row fused masked-softmax + sparse gather:
// all non-edges share weight e0=exp(-m); att@h row = (e0*colsum + sum_edges w_j h_j)/denom
__global__ __launch_bounds__(128) void attn_row(const float* __restrict__ adj, const float* __restrict__ ssrc,
                         const float* __restrict__ sdst, const float* __restrict__ hid,
                         const float* __restrict__ csum, float* __restrict__ hout, int N) {
  int i = blockIdx.x, tid = threadIdx.x;
  __shared__ unsigned short stash[CAP];
  __shared__ float wv[CAP];
  __shared__ float red[128];
  __shared__ float wtile[128];
  __shared__ int cnt;
  if (tid == 0) cnt = 0;
  __syncthreads();
  const float sd = sdst[i];
  const float* arow = adj + (long)i * N;
  float m = 0.f;
  for (int j = tid; j < N; j += 128) {
    if (arow[j] != 0.f) {
      float s = sd + ssrc[j];
      s = s > 0.f ? s : 0.01f * s;
      m = fmaxf(m, s);
      int idx = atomicAdd(&cnt, 1);
      if (idx < CAP) stash[idx] = (unsigned short)j;
    }
  }
  red[tid] = m; __syncthreads();
  for (int st = 64; st; st >>= 1) { if (tid < st) red[tid] = fmaxf(red[tid], red[tid + st]); __syncthreads(); }
  m = red[0];
  const int count = cnt;          // finalized by barriers above
  const float e0 = __expf(-m);
  float dc = 0.f;
  if (count <= CAP) {
    for (int k = tid; k < count; k += 128) {
      int j = stash[k];
      float s = sd + ssrc[j];
      s = s > 0.f ? s : 0.01f * s;
      float w = __expf(s - m) - e0;
      wv[k] = w; dc += w;
    }
  } else {
    for (int j = tid; j < N; j += 128) {
      if (arow[j] != 0.f) {
        float s = sd + ssrc[j]; s = s > 0.f ? s : 0.01f * s;
        dc += __expf(s - m) - e0;
      }
    }
  }
  __syncthreads();
  red[tid] = dc; __syncthreads();
  for (int st = 64; st; st >>= 1) { if (tid < st) red[tid] += red[tid + st]; __syncthreads(); }
  const float inv = 1.f / ((float)N * e0 + red[0]);

  const int d = tid;
  float acc = e0 * csum[d];
  if (count <= CAP) {
    #pragma unroll 4
    for (int k = 0; k < count; k++)
      acc += wv[k] * hid[(long)stash[k] * 128 + d];
  } else {
    for (int j0 = 0; j0 < N; j0 += 128) {
      int j = j0 + tid;
      float w = 0.f;
      if (j < N && arow[j] != 0.f) {
        float s = sd + ssrc[j]; s = s > 0.f ? s : 0.01f * s;
        w = __expf(s - m) - e0;
      }
      wtile[tid] = w; __syncthreads();
      int lim = min(128, N - j0);
      for (int jj = 0; jj < lim; jj++) acc += wtile[jj] * hid[(long)(j0 + jj) * 128 + d];
      __syncthreads();
    }
  }
  hout[(long)i*128 + d] = acc * inv + hid[(long)i*128 + d];
}

__global__ void transpose_wfc(const float* __restrict__ Wfc, float* __restrict__ WfcT) {
  int t = blockIdx.x * 256 + threadIdx.x;   // 64 blocks -> 16384
  int j = t >> 7, k = t & 127;
  WfcT[k*128 + j] = Wfc[t];
}

// out[n] = W_out . leaky(hid[n] @ Wfc^T + b_fc) + b_out
__global__ __launch_bounds__(128) void head_kernel(const float* __restrict__ hid, const float* __restrict__ WfcT,
                            const float* __restrict__ bfc, const float* __restrict__ Wout,
                            const float* __restrict__ bout, float* __restrict__ out, int N) {
  __shared__ float hrow[128];
  __shared__ float red[128];
  int tid = threadIdx.x;
  float bj = bfc[tid], wo = Wout[tid], bo = bout[0];
  int per = (N + (int)gridDim.x - 1) / (int)gridDim.x;
  int n0 = blockIdx.x * per, n1 = min(N, n0 + per);
  for (int n = n0; n < n1; n++) {
    __syncthreads();
    hrow[tid] = hid[(long)n*128 + tid];
    __syncthreads();
    float g = 0.f;
    #pragma unroll 8
    for (int k = 0; k < 128; k++) g += hrow[k] * WfcT[k*128 + tid];
    g += bj;
    g = g > 0.f ? g : 0.01f * g;
    red[tid] = wo * g;
    __syncthreads();
    for (int st = 64; st; st >>= 1) { if (tid < st) red[tid] += red[tid + st]; __syncthreads(); }
    if (tid == 0) out[n] = red[0] + bo;
  }
}

extern "C" void kernel_launch(void* const* d_in, const int* in_sizes, int n_in,
                              void* d_out, int out_size, void* d_ws, size_t ws_size,
                              hipStream_t stream) {
  const float* x    = (const float*)d_in[0];
  const float* adj  = (const float*)d_in[1];
  const float* Wih0 = (const float*)d_in[2];
  const float* Whh0 = (const float*)d_in[3];
  const float* bih0 = (const float*)d_in[4];
  const float* bhh0 = (const float*)d_in[5];
  const float* Wih1 = (const float*)d_in[6];
  const float* Whh1 = (const float*)d_in[7];
  const float* bih1 = (const float*)d_in[8];
  const float* bhh1 = (const float*)d_in[9];
  const float* Wtr  = (const float*)d_in[10];
  const float* btr  = (const float*)d_in[11];
  const float* avec = (const float*)d_in[12];
  const float* Wfc  = (const float*)d_in[13];
  const float* bfc  = (const float*)d_in[14];
  const float* Wout = (const float*)d_in[15];
  const float* bout = (const float*)d_in[16];
  float* out = (float*)d_out;

  const int N = 4000;
  float* ws = (float*)d_ws;
  float* sl0  = ws;                         // layer0 h slices (ping-pong)
  float* sl1  = sl0 + (size_t)N*128;
  float* c0   = sl1 + (size_t)N*128;
  float* c1   = c0  + (size_t)N*128;
  float* h1a  = c1  + (size_t)N*128;        // layer1 h / attention ping-pong
  float* h1b  = h1a + (size_t)N*128;
  float* ssrc = h1b + (size_t)N*128;
  float* sdst = ssrc + N;
  float* uv   = sdst + N;                   // 258
  float* part = uv   + 260;                 // 32*128
  float* csum = part + 32*128;              // 128
  float* WfcT = csum + 128;                 // 16384

  float* sl[2] = {sl0, sl1};
  float* hb[2] = {h1a, h1b};

  dim3 grid(63, 4, 2), blk(256);
  for (int s = 0; s <= TT; s++) {
    LayerArgs A0 = {}, A1 = {};
    A0.active = (s < TT) ? 1 : 0;
    if (A0.active) {
      int t = s;
      A0.x = x + (size_t)t * DF; A0.xs = (long)TT * DF;
      A0.h = (t == 0) ? nullptr : sl[(t + 1) & 1]; A0.hs = 128;
      A0.Wih = Wih0; A0.Whh = Whh0; A0.bih = bih0; A0.bhh = bhh0;
      A0.cin = (t == 0) ? nullptr : c0; A0.cout = c0;
      A0.hout = sl[t & 1]; A0.hos = 128;
      A0.Kx = DF;
    }
    A1.active = (s >= 1) ? 1 : 0;
    if (A1.active) {
      int t = s - 1;
      A1.x = sl[t & 1]; A1.xs = 128;      // layer0's h_t, written last launch
      A1.h = (t == 0) ? nullptr : hb[t & 1]; A1.hs = 128;
      A1.Wih = Wih1; A1.Whh = Whh1; A1.bih = bih1; A1.bhh = bhh1;
      A1.cin = (t == 0) ? nullptr : c1; A1.cout = c1;
      A1.hout = hb[(t + 1) & 1]; A1.hos = 128;
      A1.Kx = HH;
    }
    hipLaunchKernelGGL(lstm_step_dual, grid, blk, 0, stream, A0, A1, N);
  }
  // final layer-1 hidden is in h1a (step 59 writes hb[0])

  hipLaunchKernelGGL(attn_prep, dim3(1), dim3(128), 0, stream, Wtr, btr, avec, uv);
  hipLaunchKernelGGL(transpose_wfc, dim3(64), dim3(256), 0, stream, Wfc, WfcT);
  for (int r = 0; r < 2; r++) {
    const float* hid = r ? h1b : h1a;
    float* hnew = r ? h1a : h1b;
    hipLaunchKernelGGL(attn_scores, dim3(1000), dim3(256), 0, stream, hid, uv, ssrc, sdst, N);
    hipLaunchKernelGGL(colsum_part, dim3(32), dim3(128), 0, stream, hid, part, N);
    hipLaunchKernelGGL(colsum_fold, dim3(1), dim3(128), 0, stream, part, csum);
    hipLaunchKernelGGL(attn_row, dim3(N), dim3(128), 0, stream, adj, ssrc, sdst, hid, csum, hnew, N);
  }
  hipLaunchKernelGGL(head_kernel, dim3(64), dim3(128), 0, stream, h1a, WfcT, bfc, Wout, bout, out, N);
}

// Round 2
// 990.946 us; speedup vs baseline: 2.4021x; 2.4021x over previous
//
#include <hip/hip_runtime.h>

#define TT 60
#define CAP 1024

typedef __attribute__((ext_vector_type(8))) short short8v;
typedef __attribute__((ext_vector_type(16))) float f32x16;

__device__ __forceinline__ unsigned short f2bf(float f) {
  unsigned u = __float_as_uint(f);
  u += 0x7fff + ((u >> 16) & 1);
  return (unsigned short)(u >> 16);
}
__device__ __forceinline__ float bf2f(unsigned short h) {
  return __uint_as_float(((unsigned)h) << 16);
}
__device__ __forceinline__ float sigmoidf_(float x) {
  return 1.f / (1.f + __expf(-x));
}
__device__ __forceinline__ float tanhf_(float x) {
  x = fminf(fmaxf(x, -15.f), 15.f);
  float e = __expf(-2.f * x);
  return (1.f - e) / (1.f + e);
}

__device__ __forceinline__ f32x16 mfma3(short8v wh, short8v wl, short8v bh, short8v bl, f32x16 acc) {
  acc = __builtin_amdgcn_mfma_f32_32x32x16_bf16(wh, bh, acc, 0, 0, 0);
  acc = __builtin_amdgcn_mfma_f32_32x32x16_bf16(wh, bl, acc, 0, 0, 0);
  acc = __builtin_amdgcn_mfma_f32_32x32x16_bf16(wl, bh, acc, 0, 0, 0);
  return acc;
}

// ---- weight packing: W~[r~][k] -> lane-linear fragment order, split hi/lo bf16.
// r~ = tr*32 + q*8 + dl  <->  original gate row R = q*128 + (tr*8 + dl).
// frag slot: dst[((tr*ncW + c)*2 + hl)*512 + lane*8 + j], k = c*16 + (lane>>5)*8 + j
__global__ void pack_w(const float* __restrict__ Wih, const float* __restrict__ Whh,
                       int Kx, int ncW, unsigned short* __restrict__ dst) {
  int id = blockIdx.x * 256 + threadIdx.x;
  int total = 16 * ncW * 512;
  if (id >= total) return;
  int j = id & 7, lane = (id >> 3) & 63, c = (id >> 9) % ncW, tr = id / (512 * ncW);
  int rw = lane & 31, q = rw >> 3, dl = rw & 7;
  int R = q * 128 + tr * 8 + dl;
  int k = c * 16 + (lane >> 5) * 8 + j;
  float v = (k < Kx) ? Wih[(size_t)R * Kx + k] : Whh[(size_t)R * 128 + (k - Kx)];
  unsigned short hi = f2bf(v);
  unsigned short lo = f2bf(v - bf2f(hi));
  dst[((size_t)(tr * ncW + c) * 2 + 0) * 512 + lane * 8 + j] = hi;
  dst[((size_t)(tr * ncW + c) * 2 + 1) * 512 + lane * 8 + j] = lo;
}

// bias_perm[layer][r~] = bih[R] + bhh[R]
__global__ void pack_bias(const float* b0i, const float* b0h, const float* b1i, const float* b1h,
                          float* __restrict__ dst) {
  int tid = blockIdx.x * 256 + threadIdx.x;
  if (tid >= 1024) return;
  int l = tid >> 9, rr = tid & 511;
  int tr = rr >> 5, rw = rr & 31, q = rw >> 3, dl = rw & 7;
  int R = q * 128 + tr * 8 + dl;
  dst[tid] = l ? (b1i[R] + b1h[R]) : (b0i[R] + b0h[R]);
}

struct SArgs {
  const unsigned short* W; int ncW;
  const float* xf32;              // layer0: fp32 x_t (stride 960); chunk 0
  const unsigned short* Bx; int bxc;  // layer1: h0split (8 chunks)
  const unsigned short* Bh;       // own h split (null at t=0)
  const float* cin; float* cout;
  unsigned short* hout; float* hf32;
  const float* bias;
  int active;
};

// gates^T = W~ . [x|h]: D[gate-row][node] via mfma(A=W-frag, B=act-frag).
// Wave tile: 32 gate-rows (tr) x 64 nodes (2 MFMA tiles). No LDS, no barriers.
__global__ __launch_bounds__(256) void lstm_mfma(SArgs A0, SArgs A1) {
  SArgs La = blockIdx.z ? A1 : A0;
  if (!La.active) return;
  const int tid = threadIdx.x;
  const int lane = tid & 63, w = tid >> 6;
  const int tr = blockIdx.y * 4 + w;
  const int nt0 = blockIdx.x * 2;
  const bool has1 = (nt0 + 1) < 125;
  const int nt1 = has1 ? nt0 + 1 : nt0;
  const int lanelo = lane & 31, lanehi = lane >> 5;
  const int x0 = La.xf32 ? 1 : 0;
  const int nc = x0 + La.bxc + (La.Bh ? 8 : 0);

  f32x16 acc0, acc1;
  #pragma unroll
  for (int r = 0; r < 16; r++) {
    float b = La.bias[tr * 32 + (r & 3) + 8 * (r >> 2) + 4 * lanehi];
    acc0[r] = b; acc1[r] = b;
  }

  auto loadW = [&](int c, short8v& wh, short8v& wl) {
    const unsigned short* p = La.W + ((size_t)(tr * La.ncW + c) * 2) * 512 + lane * 8;
    wh = *(const short8v*)p;
    wl = *(const short8v*)(p + 512);
  };
  auto loadB = [&](int c, int nt, short8v& bh, short8v& bl) {
    if (x0 && c == 0) {
      const float* xp = La.xf32 + (size_t)(nt * 32 + lanelo) * 960 + lanehi * 8;
      float4 f0 = *(const float4*)xp, f1 = *(const float4*)(xp + 4);
      float fv[8] = {f0.x, f0.y, f0.z, f0.w, f1.x, f1.y, f1.z, f1.w};
      union { short8v v; unsigned short s[8]; } H, L;
      #pragma unroll
      for (int e = 0; e < 8; e++) {
        unsigned short h = f2bf(fv[e]);
        H.s[e] = h; L.s[e] = f2bf(fv[e] - bf2f(h));
      }
      bh = H.v; bl = L.v;
    } else {
      int cc = c - x0;
      const unsigned short* base; size_t off;
      if (cc < La.bxc) { base = La.Bx; off = ((size_t)(nt * La.bxc + cc) * 2) * 512; }
      else             { base = La.Bh; off = ((size_t)(nt * 8 + (cc - La.bxc)) * 2) * 512; }
      const unsigned short* p = base + off + lane * 8;
      bh = *(const short8v*)p;
      bl = *(const short8v*)(p + 512);
    }
  };

  short8v wh0, wl0, b0h0, b0l0, b1h0, b1l0;
  short8v wh1, wl1, b0h1, b0l1, b1h1, b1l1;
  loadW(0, wh0, wl0); loadB(0, nt0, b0h0, b0l0); loadB(0, nt1, b1h0, b1l0);
  for (int c = 0; c < nc; c += 2) {
    if (c + 1 < nc) { loadW(c + 1, wh1, wl1); loadB(c + 1, nt0, b0h1, b0l1); loadB(c + 1, nt1, b1h1, b1l1); }
    acc0 = mfma3(wh0, wl0, b0h0, b0l0, acc0);
    acc1 = mfma3(wh0, wl0, b1h0, b1l0, acc1);
    if (c + 2 < nc) { loadW(c + 2, wh0, wl0); loadB(c + 2, nt0, b0h0, b0l0); loadB(c + 2, nt1, b1h0, b1l0); }
    if (c + 1 < nc) {
      acc0 = mfma3(wh1, wl1, b0h1, b0l1, acc0);
      acc1 = mfma3(wh1, wl1, b1h1, b1l1, acc1);
    }
  }

  auto epi = [&](int nt, const f32x16& acc) {
    int node = nt * 32 + lanelo;
    int D0 = tr * 8 + 4 * lanehi;
    float colda[4] = {0.f, 0.f, 0.f, 0.f};
    if (La.cin) {
      float4 c4 = *(const float4*)(La.cin + (size_t)node * 128 + D0);
      colda[0] = c4.x; colda[1] = c4.y; colda[2] = c4.z; colda[3] = c4.w;
    }
    float co[4], ho[4];
    #pragma unroll
    for (int dl = 0; dl < 4; dl++) {
      float gi = acc[dl], gf = acc[4 + dl], gg = acc[8 + dl], go = acc[12 + dl];
      float i_ = sigmoidf_(gi), f_ = sigmoidf_(gf);
      float g_ = tanhf_(gg),    o_ = sigmoidf_(go);
      float cn = f_ * colda[dl] + i_ * g_;
      co[dl] = cn;
      ho[dl] = o_ * tanhf_(cn);
    }
    *(float4*)(La.cout + (size_t)node * 128 + D0) = make_float4(co[0], co[1], co[2], co[3]);
    if (La.hf32)
      *(float4*)(La.hf32 + (size_t)node * 128 + D0) = make_float4(ho[0], ho[1], ho[2], ho[3]);
    size_t hb = ((size_t)(nt * 8 + (tr >> 1)) * 2) * 512 + (lanelo + 32 * (tr & 1)) * 8 + 4 * lanehi;
    unsigned short hs[4], ls[4];
    #pragma unroll
    for (int dl = 0; dl < 4; dl++) {
      unsigned short h = f2bf(ho[dl]);
      hs[dl] = h; ls[dl] = f2bf(ho[dl] - bf2f(h));
    }
    *(ushort4*)(La.hout + hb)       = make_ushort4(hs[0], hs[1], hs[2], hs[3]);
    *(ushort4*)(La.hout + 512 + hb) = make_ushort4(ls[0], ls[1], ls[2], ls[3]);
  };
  epi(nt0, acc0);
  if (has1) epi(nt1, acc1);
}

// ---------------- attention (unchanged from passing round) ----------------
__global__ void attn_prep(const float* __restrict__ Wt, const float* __restrict__ bt,
                          const float* __restrict__ a, float* __restrict__ uv) {
  int k = threadIdx.x;
  float us = 0.f, ud = 0.f;
  for (int j = 0; j < 128; j++) {
    float w = Wt[j * 128 + k];
    us += a[j] * w;
    ud += a[128 + j] * w;
  }
  uv[k] = us; uv[128 + k] = ud;
  __shared__ float red[128];
  red[k] = bt[k] * a[k];
  __syncthreads();
  for (int st = 64; st; st >>= 1) { if (k < st) red[k] += red[k + st]; __syncthreads(); }
  if (k == 0) uv[256] = red[0];
  __syncthreads();
  red[k] = bt[k] * a[128 + k];
  __syncthreads();
  for (int st = 64; st; st >>= 1) { if (k < st) red[k] += red[k + st]; __syncthreads(); }
  if (k == 0) uv[257] = red[0];
}

__global__ void attn_scores(const float* __restrict__ hid, const float* __restrict__ uv,
                            float* __restrict__ ssrc, float* __restrict__ sdst, int N) {
  int wave = threadIdx.x >> 6, lane = threadIdx.x & 63;
  int i = blockIdx.x * 4 + wave;
  if (i >= N) return;
  float h0 = hid[(long)i * 128 + lane], h1 = hid[(long)i * 128 + 64 + lane];
  float us = h0 * uv[lane] + h1 * uv[64 + lane];
  float ud = h0 * uv[128 + lane] + h1 * uv[192 + lane];
  for (int off = 32; off; off >>= 1) { us += __shfl_down(us, off); ud += __shfl_down(ud, off); }
  if (lane == 0) { ssrc[i] = us + uv[256]; sdst[i] = ud + uv[257]; }
}

__global__ void colsum_part(const float* __restrict__ hid, float* __restrict__ part, int N) {
  int d = threadIdx.x, b = blockIdx.x;
  int per = (N + 31) / 32;
  int n0 = b * per, n1 = min(N, n0 + per);
  float s = 0.f;
  for (int n = n0; n < n1; n++) s += hid[(long)n * 128 + d];
  part[b * 128 + d] = s;
}
__global__ void colsum_fold(const float* __restrict__ part, float* __restrict__ csum) {
  int d = threadIdx.x;
  float s = 0.f;
  for (int b = 0; b < 32; b++) s += part[b * 128 + d];
  csum[d] = s;
}

__global__ __launch_bounds__(128) void attn_row(const float* __restrict__ adj, const float* __restrict__ ssrc,
                         const float* __restrict__ sdst, const float* __restrict__ hid,
                         const float* __restrict__ csum, float* __restrict__ hout, int N) {
  int i = blockIdx.x, tid = threadIdx.x;
  __shared__ unsigned short stash[CAP];
  __shared__ float wv[CAP];
  __shared__ float red[128];
  __shared__ float wtile[128];
  __shared__ int cnt;
  if (tid == 0) cnt = 0;
  __syncthreads();
  const float sd = sdst[i];
  const float* arow = adj + (long)i * N;
  float m = 0.f;
  for (int j = tid; j < N; j += 128) {
    if (arow[j] != 0.f) {
      float s = sd + ssrc[j];
      s = s > 0.f ? s : 0.01f * s;
      m = fmaxf(m, s);
      int idx = atomicAdd(&cnt, 1);
      if (idx < CAP) stash[idx] = (unsigned short)j;
    }
  }
  red[tid] = m; __syncthreads();
  for (int st = 64; st; st >>= 1) { if (tid < st) red[tid] = fmaxf(red[tid], red[tid + st]); __syncthreads(); }
  m = red[0];
  const int count = cnt;
  const float e0 = __expf(-m);
  float dc = 0.f;
  if (count <= CAP) {
    for (int k = tid; k < count; k += 128) {
      int j = stash[k];
      float s = sd + ssrc[j];
      s = s > 0.f ? s : 0.01f * s;
      float w = __expf(s - m) - e0;
      wv[k] = w; dc += w;
    }
  } else {
    for (int j = tid; j < N; j += 128) {
      if (arow[j] != 0.f) {
        float s = sd + ssrc[j]; s = s > 0.f ? s : 0.01f * s;
        dc += __expf(s - m) - e0;
      }
    }
  }
  __syncthreads();
  red[tid] = dc; __syncthreads();
  for (int st = 64; st; st >>= 1) { if (tid < st) red[tid] += red[tid + st]; __syncthreads(); }
  const float inv = 1.f / ((float)N * e0 + red[0]);

  const int d = tid;
  float acc = e0 * csum[d];
  if (count <= CAP) {
    #pragma unroll 4
    for (int k = 0; k < count; k++)
      acc += wv[k] * hid[(long)stash[k] * 128 + d];
  } else {
    for (int j0 = 0; j0 < N; j0 += 128) {
      int j = j0 + tid;
      float w = 0.f;
      if (j < N && arow[j] != 0.f) {
        float s = sd + ssrc[j]; s = s > 0.f ? s : 0.01f * s;
        w = __expf(s - m) - e0;
      }
      wtile[tid] = w; __syncthreads();
      int lim = min(128, N - j0);
      for (int jj = 0; jj < lim; jj++) acc += wtile[jj] * hid[(long)(j0 + jj) * 128 + d];
      __syncthreads();
    }
  }
  hout[(long)i * 128 + d] = acc * inv + hid[(long)i * 128 + d];
}

// out[n] = Wout . leaky(hid[n] @ Wfc^T + bfc) + bout
// 125 blocks x 256 thr; 32 rows/block staged in LDS; 8 threads/row x 16 j each.
__global__ __launch_bounds__(256) void head_kernel(const float* __restrict__ hid, const float* __restrict__ Wfc,
                            const float* __restrict__ bfc, const float* __restrict__ Wout,
                            const float* __restrict__ bout, float* __restrict__ out, int N) {
  __shared__ float hL[32 * 132];
  int tid = threadIdx.x;
  int row0 = blockIdx.x * 32;
  for (int idx = tid; idx < 32 * 128; idx += 256) {
    int rr = idx >> 7, kk = idx & 127;
    hL[rr * 132 + kk] = hid[(size_t)(row0 + rr) * 128 + kk];
  }
  __syncthreads();
  int r = tid >> 3, js = tid & 7;
  float acc = 0.f;
  #pragma unroll
  for (int jj = 0; jj < 16; jj++) {
    int j = js * 16 + jj;
    float g = bfc[j];
    const float* wr = Wfc + (size_t)j * 128;
    const float* hr = hL + r * 132;
    #pragma unroll 8
    for (int k = 0; k < 128; k += 4) {
      float4 h4 = *(const float4*)(hr + k);
      float4 w4 = *(const float4*)(wr + k);
      g += h4.x * w4.x + h4.y * w4.y + h4.z * w4.z + h4.w * w4.w;
    }
    g = g > 0.f ? g : 0.01f * g;
    acc += Wout[j] * g;
  }
  acc += __shfl_down(acc, 4, 8);
  acc += __shfl_down(acc, 2, 8);
  acc += __shfl_down(acc, 1, 8);
  if ((tid & 7) == 0) out[row0 + r] = acc + bout[0];
}

extern "C" void kernel_launch(void* const* d_in, const int* in_sizes, int n_in,
                              void* d_out, int out_size, void* d_ws, size_t ws_size,
                              hipStream_t stream) {
  const float* x    = (const float*)d_in[0];
  const float* adj  = (const float*)d_in[1];
  const float* Wih0 = (const float*)d_in[2];
  const float* Whh0 = (const float*)d_in[3];
  const float* bih0 = (const float*)d_in[4];
  const float* bhh0 = (const float*)d_in[5];
  const float* Wih1 = (const float*)d_in[6];
  const float* Whh1 = (const float*)d_in[7];
  const float* bih1 = (const float*)d_in[8];
  const float* bhh1 = (const float*)d_in[9];
  const float* Wtr  = (const float*)d_in[10];
  const float* btr  = (const float*)d_in[11];
  const float* avec = (const float*)d_in[12];
  const float* Wfc  = (const float*)d_in[13];
  const float* bfc  = (const float*)d_in[14];
  const float* Wout = (const float*)d_in[15];
  const float* bout = (const float*)d_in[16];
  float* out = (float*)d_out;

  const int N = 4000;
  char* base = (char*)d_ws;
  size_t off = 0;
  auto alloc = [&](size_t bytes) { char* p = base + off; off += (bytes + 255) & ~(size_t)255; return p; };

  float* c0   = (float*)alloc((size_t)N * 128 * 4);
  float* c1   = (float*)alloc((size_t)N * 128 * 4);
  float* h1a  = (float*)alloc((size_t)N * 128 * 4);
  float* h1b  = (float*)alloc((size_t)N * 128 * 4);
  unsigned short* h0s0 = (unsigned short*)alloc((size_t)125 * 8 * 2 * 512 * 2);
  unsigned short* h0s1 = (unsigned short*)alloc((size_t)125 * 8 * 2 * 512 * 2);
  unsigned short* h1s0 = (unsigned short*)alloc((size_t)125 * 8 * 2 * 512 * 2);
  unsigned short* h1s1 = (unsigned short*)alloc((size_t)125 * 8 * 2 * 512 * 2);
  unsigned short* w0f  = (unsigned short*)alloc((size_t)16 * 9 * 2 * 512 * 2);
  unsigned short* w1f  = (unsigned short*)alloc((size_t)16 * 16 * 2 * 512 * 2);
  float* biasP = (float*)alloc(1024 * 4);      // [0..511]=layer0, [512..1023]=layer1
  float* ssrc = (float*)alloc(N * 4);
  float* sdst = (float*)alloc(N * 4);
  float* uv   = (float*)alloc(272 * 4);
  float* part = (float*)alloc(4096 * 4);
  float* csum = (float*)alloc(128 * 4);

  unsigned short* h0s[2] = {h0s0, h0s1};
  unsigned short* h1s[2] = {h1s0, h1s1};

  hipLaunchKernelGGL(pack_w, dim3(288), dim3(256), 0, stream, Wih0, Whh0, 16, 9, w0f);
  hipLaunchKernelGGL(pack_w, dim3(512), dim3(256), 0, stream, Wih1, Whh1, 128, 16, w1f);
  hipLaunchKernelGGL(pack_bias, dim3(4), dim3(256), 0, stream, bih0, bhh0, bih1, bhh1, biasP);

  dim3 grid(63, 4, 2), blk(256);
  for (int s = 0; s <= TT; s++) {
    SArgs A0 = {}, A1 = {};
    A0.active = (s < TT) ? 1 : 0;
    if (A0.active) {
      int t = s;
      A0.W = w0f; A0.ncW = 9;
      A0.xf32 = x + (size_t)t * 16;
      A0.Bx = nullptr; A0.bxc = 0;
      A0.Bh = (t == 0) ? nullptr : h0s[(t + 1) & 1];
      A0.cin = (t == 0) ? nullptr : c0; A0.cout = c0;
      A0.hout = h0s[t & 1]; A0.hf32 = nullptr;
      A0.bias = biasP;
    }
    A1.active = (s >= 1) ? 1 : 0;
    if (A1.active) {
      int t = s - 1;
      A1.W = w1f; A1.ncW = 16;
      A1.xf32 = nullptr;
      A1.Bx = h0s[t & 1]; A1.bxc = 8;
      A1.Bh = (t == 0) ? nullptr : h1s[(t + 1) & 1];
      A1.cin = (t == 0) ? nullptr : c1; A1.cout = c1;
      A1.hout = h1s[t & 1]; A1.hf32 = h1a;
      A1.bias = biasP + 512;
    }
    hipLaunchKernelGGL(lstm_mfma, grid, blk, 0, stream, A0, A1);
  }

  hipLaunchKernelGGL(attn_prep, dim3(1), dim3(128), 0, stream, Wtr, btr, avec, uv);
  for (int r = 0; r < 2; r++) {
    const float* hid = r ? h1b : h1a;
    float* hnew = r ? h1a : h1b;
    hipLaunchKernelGGL(attn_scores, dim3(1000), dim3(256), 0, stream, hid, uv, ssrc, sdst, N);
    hipLaunchKernelGGL(colsum_part, dim3(32), dim3(128), 0, stream, hid, part, N);
    hipLaunchKernelGGL(colsum_fold, dim3(1), dim3(128), 0, stream, part, csum);
    hipLaunchKernelGGL(attn_row, dim3(N), dim3(128), 0, stream, adj, ssrc, sdst, hid, csum, hnew, N);
  }
  hipLaunchKernelGGL(head_kernel, dim3(125), dim3(256), 0, stream, h1a, Wfc, bfc, Wout, bout, out, N);
}

// Round 3
// 919.833 us; speedup vs baseline: 2.5878x; 1.0773x over previous
//
#include <hip/hip_runtime.h>

#define TT 60
#define CAP 1024

typedef __attribute__((ext_vector_type(8))) short short8v;
typedef __attribute__((ext_vector_type(16))) float f32x16;

__device__ __forceinline__ unsigned short f2bf(float f) {
  unsigned u = __float_as_uint(f);
  u += 0x7fff + ((u >> 16) & 1);
  return (unsigned short)(u >> 16);
}
__device__ __forceinline__ float bf2f(unsigned short h) {
  return __uint_as_float(((unsigned)h) << 16);
}
__device__ __forceinline__ float sigmoidf_(float x) {
  return 1.f / (1.f + __expf(-x));
}
__device__ __forceinline__ float tanhf_(float x) {
  x = fminf(fmaxf(x, -15.f), 15.f);
  float e = __expf(-2.f * x);
  return (1.f - e) / (1.f + e);
}

#define MF(a, b, c) __builtin_amdgcn_mfma_f32_32x32x16_bf16(a, b, c, 0, 0, 0)

// ---- weight packing: W~[r~][k] -> lane-linear fragment order, split hi/lo bf16.
// r~ = tr*32 + q*8 + dl  <->  original gate row R = q*128 + (tr*8 + dl).
// frag slot: dst[((tr*ncW + c)*2 + hl)*512 + lane*8 + j], k = c*16 + (lane>>5)*8 + j
__global__ void pack_w(const float* __restrict__ Wih, const float* __restrict__ Whh,
                       int Kx, int ncW, unsigned short* __restrict__ dst) {
  int id = blockIdx.x * 256 + threadIdx.x;
  int total = 16 * ncW * 512;
  if (id >= total) return;
  int j = id & 7, lane = (id >> 3) & 63, c = (id >> 9) % ncW, tr = id / (512 * ncW);
  int rw = lane & 31, q = rw >> 3, dl = rw & 7;
  int R = q * 128 + tr * 8 + dl;
  int k = c * 16 + (lane >> 5) * 8 + j;
  float v = (k < Kx) ? Wih[(size_t)R * Kx + k] : Whh[(size_t)R * 128 + (k - Kx)];
  unsigned short hi = f2bf(v);
  unsigned short lo = f2bf(v - bf2f(hi));
  dst[((size_t)(tr * ncW + c) * 2 + 0) * 512 + lane * 8 + j] = hi;
  dst[((size_t)(tr * ncW + c) * 2 + 1) * 512 + lane * 8 + j] = lo;
}

// bias_perm[layer][r~] = bih[R] + bhh[R]
__global__ void pack_bias(const float* b0i, const float* b0h, const float* b1i, const float* b1h,
                          float* __restrict__ dst) {
  int tid = blockIdx.x * 256 + threadIdx.x;
  if (tid >= 1024) return;
  int l = tid >> 9, rr = tid & 511;
  int tr = rr >> 5, rw = rr & 31, q = rw >> 3, dl = rw & 7;
  int R = q * 128 + tr * 8 + dl;
  dst[tid] = l ? (b1i[R] + b1h[R]) : (b0i[R] + b0h[R]);
}

struct SArgs {
  const unsigned short* W; int ncW;
  const float* xf32;              // layer0: fp32 x_t (stride 960); chunk 0
  const unsigned short* Bx; int bxc;  // layer1: h0split (8 chunks)
  const unsigned short* Bh;       // own h split (null at t=0)
  const float* cin; float* cout;
  unsigned short* hout; float* hf32;
  const float* bias;
  int active;
};

struct Ch {
  short8v wh, wl, b0h, b0l, b1h, b1l;
};

// gates^T = W~ . [x|h]: D[gate-row][node] via mfma(A=W-frag, B=act-frag).
// Wave tile: 32 gate-rows (tr) x 64 nodes (2 MFMA tiles). No LDS, no barriers.
// 3-deep register prefetch (named buffers -> static indexing), interleaved
// acc0/acc1 MFMA chains (no dependent back-to-back MFMA).
__global__ __launch_bounds__(256) void lstm_mfma(SArgs A0, SArgs A1) {
  SArgs La = blockIdx.z ? A1 : A0;
  if (!La.active) return;
  const int tid = threadIdx.x;
  const int lane = tid & 63, w = tid >> 6;
  const int tr = blockIdx.y * 4 + w;
  const int nt0 = blockIdx.x * 2;
  const bool has1 = (nt0 + 1) < 125;
  const int nt1 = has1 ? nt0 + 1 : nt0;
  const int lanelo = lane & 31, lanehi = lane >> 5;
  const int x0 = La.xf32 ? 1 : 0;
  const int nc = x0 + La.bxc + (La.Bh ? 8 : 0);

  f32x16 acc0, acc1;
  #pragma unroll
  for (int r = 0; r < 16; r++) {
    float b = La.bias[tr * 32 + (r & 3) + 8 * (r >> 2) + 4 * lanehi];
    acc0[r] = b; acc1[r] = b;
  }

  auto loadCh = [&](Ch& P, int c) {
    {
      const unsigned short* p = La.W + ((size_t)(tr * La.ncW + c) * 2) * 512 + lane * 8;
      P.wh = *(const short8v*)p;
      P.wl = *(const short8v*)(p + 512);
    }
    if (x0 && c == 0) {
      const float* xp0 = La.xf32 + (size_t)(nt0 * 32 + lanelo) * 960 + lanehi * 8;
      const float* xp1 = La.xf32 + (size_t)(nt1 * 32 + lanelo) * 960 + lanehi * 8;
      float4 a0 = *(const float4*)xp0, a1 = *(const float4*)(xp0 + 4);
      float4 b0 = *(const float4*)xp1, b1 = *(const float4*)(xp1 + 4);
      float f0[8] = {a0.x, a0.y, a0.z, a0.w, a1.x, a1.y, a1.z, a1.w};
      float f1[8] = {b0.x, b0.y, b0.z, b0.w, b1.x, b1.y, b1.z, b1.w};
      union { short8v v; unsigned short s[8]; } H0, L0, H1, L1;
      #pragma unroll
      for (int e = 0; e < 8; e++) {
        unsigned short h0 = f2bf(f0[e]); H0.s[e] = h0; L0.s[e] = f2bf(f0[e] - bf2f(h0));
        unsigned short h1 = f2bf(f1[e]); H1.s[e] = h1; L1.s[e] = f2bf(f1[e] - bf2f(h1));
      }
      P.b0h = H0.v; P.b0l = L0.v; P.b1h = H1.v; P.b1l = L1.v;
    } else {
      int cc = c - x0;
      const unsigned short* base; size_t soff; int cl;
      if (cc < La.bxc) { base = La.Bx; soff = 0; cl = cc; }
      else             { base = La.Bh; soff = 0; cl = cc - La.bxc; }
      const unsigned short* p0 = base + ((size_t)(nt0 * (cc < La.bxc ? La.bxc : 8) + cl) * 2) * 512 + lane * 8;
      const unsigned short* p1 = base + ((size_t)(nt1 * (cc < La.bxc ? La.bxc : 8) + cl) * 2) * 512 + lane * 8;
      (void)soff;
      P.b0h = *(const short8v*)p0;
      P.b0l = *(const short8v*)(p0 + 512);
      P.b1h = *(const short8v*)p1;
      P.b1l = *(const short8v*)(p1 + 512);
    }
  };

  auto compCh = [&](const Ch& P) {
    acc0 = MF(P.wh, P.b0h, acc0);
    acc1 = MF(P.wh, P.b1h, acc1);
    acc0 = MF(P.wh, P.b0l, acc0);
    acc1 = MF(P.wh, P.b1l, acc1);
    acc0 = MF(P.wl, P.b0h, acc0);
    acc1 = MF(P.wl, P.b1h, acc1);
  };

  Ch p0, p1, p2;
  loadCh(p0, 0);
  if (nc > 1) loadCh(p1, 1);
  if (nc > 2) loadCh(p2, 2);
  for (int c = 0; c < nc; c += 3) {
    compCh(p0);
    if (c + 3 < nc) loadCh(p0, c + 3);
    if (c + 1 < nc) {
      compCh(p1);
      if (c + 4 < nc) loadCh(p1, c + 4);
    }
    if (c + 2 < nc) {
      compCh(p2);
      if (c + 5 < nc) loadCh(p2, c + 5);
    }
  }

  auto epi = [&](int nt, const f32x16& acc) {
    int node = nt * 32 + lanelo;
    int D0 = tr * 8 + 4 * lanehi;
    float colda[4] = {0.f, 0.f, 0.f, 0.f};
    if (La.cin) {
      float4 c4 = *(const float4*)(La.cin + (size_t)node * 128 + D0);
      colda[0] = c4.x; colda[1] = c4.y; colda[2] = c4.z; colda[3] = c4.w;
    }
    float co[4], ho[4];
    #pragma unroll
    for (int dl = 0; dl < 4; dl++) {
      float gi = acc[dl], gf = acc[4 + dl], gg = acc[8 + dl], go = acc[12 + dl];
      float i_ = sigmoidf_(gi), f_ = sigmoidf_(gf);
      float g_ = tanhf_(gg),    o_ = sigmoidf_(go);
      float cn = f_ * colda[dl] + i_ * g_;
      co[dl] = cn;
      ho[dl] = o_ * tanhf_(cn);
    }
    *(float4*)(La.cout + (size_t)node * 128 + D0) = make_float4(co[0], co[1], co[2], co[3]);
    if (La.hf32)
      *(float4*)(La.hf32 + (size_t)node * 128 + D0) = make_float4(ho[0], ho[1], ho[2], ho[3]);
    size_t hb = ((size_t)(nt * 8 + (tr >> 1)) * 2) * 512 + (lanelo + 32 * (tr & 1)) * 8 + 4 * lanehi;
    unsigned short hs[4], ls[4];
    #pragma unroll
    for (int dl = 0; dl < 4; dl++) {
      unsigned short h = f2bf(ho[dl]);
      hs[dl] = h; ls[dl] = f2bf(ho[dl] - bf2f(h));
    }
    *(ushort4*)(La.hout + hb)       = make_ushort4(hs[0], hs[1], hs[2], hs[3]);
    *(ushort4*)(La.hout + 512 + hb) = make_ushort4(ls[0], ls[1], ls[2], ls[3]);
  };
  epi(nt0, acc0);
  if (has1) epi(nt1, acc1);
}

// ---------------- attention ----------------
__global__ void attn_prep(const float* __restrict__ Wt, const float* __restrict__ bt,
                          const float* __restrict__ a, float* __restrict__ uv) {
  int k = threadIdx.x;
  float us = 0.f, ud = 0.f;
  for (int j = 0; j < 128; j++) {
    float w = Wt[j * 128 + k];
    us += a[j] * w;
    ud += a[128 + j] * w;
  }
  uv[k] = us; uv[128 + k] = ud;
  __shared__ float red[128];
  red[k] = bt[k] * a[k];
  __syncthreads();
  for (int st = 64; st; st >>= 1) { if (k < st) red[k] += red[k + st]; __syncthreads(); }
  if (k == 0) uv[256] = red[0];
  __syncthreads();
  red[k] = bt[k] * a[128 + k];
  __syncthreads();
  for (int st = 64; st; st >>= 1) { if (k < st) red[k] += red[k + st]; __syncthreads(); }
  if (k == 0) uv[257] = red[0];
}

__global__ void attn_scores(const float* __restrict__ hid, const float* __restrict__ uv,
                            float* __restrict__ ssrc, float* __restrict__ sdst, int N) {
  int wave = threadIdx.x >> 6, lane = threadIdx.x & 63;
  int i = blockIdx.x * 4 + wave;
  if (i >= N) return;
  float h0 = hid[(long)i * 128 + lane], h1 = hid[(long)i * 128 + 64 + lane];
  float us = h0 * uv[lane] + h1 * uv[64 + lane];
  float ud = h0 * uv[128 + lane] + h1 * uv[192 + lane];
  for (int off = 32; off; off >>= 1) { us += __shfl_down(us, off); ud += __shfl_down(ud, off); }
  if (lane == 0) { ssrc[i] = us + uv[256]; sdst[i] = ud + uv[257]; }
}

__global__ void colsum_part(const float* __restrict__ hid, float* __restrict__ part, int N) {
  int d = threadIdx.x, b = blockIdx.x;
  int per = (N + 31) / 32;
  int n0 = b * per, n1 = min(N, n0 + per);
  float s = 0.f;
  for (int n = n0; n < n1; n++) s += hid[(long)n * 128 + d];
  part[b * 128 + d] = s;
}
__global__ void colsum_fold(const float* __restrict__ part, float* __restrict__ csum) {
  int d = threadIdx.x;
  float s = 0.f;
  for (int b = 0; b < 32; b++) s += part[b * 128 + d];
  csum[d] = s;
}

__global__ __launch_bounds__(128) void attn_row(const float* __restrict__ adj, const float* __restrict__ ssrc,
                         const float* __restrict__ sdst, const float* __restrict__ hid,
                         const float* __restrict__ csum, float* __restrict__ hout, int N) {
  int i = blockIdx.x, tid = threadIdx.x;
  __shared__ unsigned short stash[CAP];
  __shared__ float wv[CAP];
  __shared__ float red[128];
  __shared__ float wtile[128];
  __shared__ int cnt;
  if (tid == 0) cnt = 0;
  __syncthreads();
  const float sd = sdst[i];
  const float* arow = adj + (long)i * N;
  float m = 0.f;
  for (int j = tid; j < N; j += 128) {
    if (arow[j] != 0.f) {
      float s = sd + ssrc[j];
      s = s > 0.f ? s : 0.01f * s;
      m = fmaxf(m, s);
      int idx = atomicAdd(&cnt, 1);
      if (idx < CAP) stash[idx] = (unsigned short)j;
    }
  }
  red[tid] = m; __syncthreads();
  for (int st = 64; st; st >>= 1) { if (tid < st) red[tid] = fmaxf(red[tid], red[tid + st]); __syncthreads(); }
  m = red[0];
  const int count = cnt;
  const float e0 = __expf(-m);
  float dc = 0.f;
  if (count <= CAP) {
    for (int k = tid; k < count; k += 128) {
      int j = stash[k];
      float s = sd + ssrc[j];
      s = s > 0.f ? s : 0.01f * s;
      float w = __expf(s - m) - e0;
      wv[k] = w; dc += w;
    }
  } else {
    for (int j = tid; j < N; j += 128) {
      if (arow[j] != 0.f) {
        float s = sd + ssrc[j]; s = s > 0.f ? s : 0.01f * s;
        dc += __expf(s - m) - e0;
      }
    }
  }
  __syncthreads();
  red[tid] = dc; __syncthreads();
  for (int st = 64; st; st >>= 1) { if (tid < st) red[tid] += red[tid + st]; __syncthreads(); }
  const float inv = 1.f / ((float)N * e0 + red[0]);

  const int d = tid;
  float acc = e0 * csum[d];
  if (count <= CAP) {
    #pragma unroll 4
    for (int k = 0; k < count; k++)
      acc += wv[k] * hid[(long)stash[k] * 128 + d];
  } else {
    for (int j0 = 0; j0 < N; j0 += 128) {
      int j = j0 + tid;
      float w = 0.f;
      if (j < N && arow[j] != 0.f) {
        float s = sd + ssrc[j]; s = s > 0.f ? s : 0.01f * s;
        w = __expf(s - m) - e0;
      }
      wtile[tid] = w; __syncthreads();
      int lim = min(128, N - j0);
      for (int jj = 0; jj < lim; jj++) acc += wtile[jj] * hid[(long)(j0 + jj) * 128 + d];
      __syncthreads();
    }
  }
  hout[(long)i * 128 + d] = acc * inv + hid[(long)i * 128 + d];
}

// out[n] = Wout . leaky(hid[n] @ Wfc^T + bfc) + bout
// 125 blocks x 256 thr. Wfc staged TRANSPOSED [k][j] in LDS (two 64-k halves,
// 40KB), conflict-free reads. Thread tile: 4 rows x 4 j (j = js + 32*ji).
__global__ __launch_bounds__(256) void head_kernel(const float* __restrict__ hid, const float* __restrict__ Wfc,
                            const float* __restrict__ bfc, const float* __restrict__ Wout,
                            const float* __restrict__ bout, float* __restrict__ out, int N) {
  __shared__ float wT[64 * 128];   // [k][j]
  __shared__ float hL[32 * 64];    // [r][k]
  const int tid = threadIdx.x;
  const int row0 = blockIdx.x * 32;
  const int js = tid & 31, r0 = (tid >> 5) * 4;

  float fc[4][4];
  #pragma unroll
  for (int ri = 0; ri < 4; ri++)
    #pragma unroll
    for (int ji = 0; ji < 4; ji++) fc[ri][ji] = 0.f;

  for (int half = 0; half < 2; half++) {
    const int k0 = half * 64;
    __syncthreads();
    {
      int jj = tid & 127, kg = (tid >> 7) * 32;
      for (int kk = 0; kk < 32; kk++)
        wT[(kg + kk) * 128 + jj] = Wfc[(size_t)jj * 128 + k0 + kg + kk];
      int rr = tid >> 3, ks = (tid & 7) * 8;
      float4 a = *(const float4*)(hid + (size_t)(row0 + rr) * 128 + k0 + ks);
      float4 b = *(const float4*)(hid + (size_t)(row0 + rr) * 128 + k0 + ks + 4);
      *(float4*)(hL + rr * 64 + ks) = a;
      *(float4*)(hL + rr * 64 + ks + 4) = b;
    }
    __syncthreads();
    #pragma unroll 4
    for (int k = 0; k < 64; k++) {
      float h0 = hL[(r0 + 0) * 64 + k];
      float h1 = hL[(r0 + 1) * 64 + k];
      float h2 = hL[(r0 + 2) * 64 + k];
      float h3 = hL[(r0 + 3) * 64 + k];
      #pragma unroll
      for (int ji = 0; ji < 4; ji++) {
        float wv = wT[k * 128 + js + 32 * ji];
        fc[0][ji] += h0 * wv;
        fc[1][ji] += h1 * wv;
        fc[2][ji] += h2 * wv;
        fc[3][ji] += h3 * wv;
      }
    }
  }

  float wo[4], bj[4];
  #pragma unroll
  for (int ji = 0; ji < 4; ji++) { wo[ji] = Wout[js + 32 * ji]; bj[ji] = bfc[js + 32 * ji]; }
  float bo = bout[0];
  #pragma unroll
  for (int ri = 0; ri < 4; ri++) {
    float v = 0.f;
    #pragma unroll
    for (int ji = 0; ji < 4; ji++) {
      float g = fc[ri][ji] + bj[ji];
      g = g > 0.f ? g : 0.01f * g;
      v += wo[ji] * g;
    }
    v += __shfl_down(v, 16);
    v += __shfl_down(v, 8);
    v += __shfl_down(v, 4);
    v += __shfl_down(v, 2);
    v += __shfl_down(v, 1);
    if (js == 0) out[row0 + r0 + ri] = v + bo;
  }
}

extern "C" void kernel_launch(void* const* d_in, const int* in_sizes, int n_in,
                              void* d_out, int out_size, void* d_ws, size_t ws_size,
                              hipStream_t stream) {
  const float* x    = (const float*)d_in[0];
  const float* adj  = (const float*)d_in[1];
  const float* Wih0 = (const float*)d_in[2];
  const float* Whh0 = (const float*)d_in[3];
  const float* bih0 = (const float*)d_in[4];
  const float* bhh0 = (const float*)d_in[5];
  const float* Wih1 = (const float*)d_in[6];
  const float* Whh1 = (const float*)d_in[7];
  const float* bih1 = (const float*)d_in[8];
  const float* bhh1 = (const float*)d_in[9];
  const float* Wtr  = (const float*)d_in[10];
  const float* btr  = (const float*)d_in[11];
  const float* avec = (const float*)d_in[12];
  const float* Wfc  = (const float*)d_in[13];
  const float* bfc  = (const float*)d_in[14];
  const float* Wout = (const float*)d_in[15];
  const float* bout = (const float*)d_in[16];
  float* out = (float*)d_out;

  const int N = 4000;
  char* base = (char*)d_ws;
  size_t off = 0;
  auto alloc = [&](size_t bytes) { char* p = base + off; off += (bytes + 255) & ~(size_t)255; return p; };

  float* c0   = (float*)alloc((size_t)N * 128 * 4);
  float* c1   = (float*)alloc((size_t)N * 128 * 4);
  float* h1a  = (float*)alloc((size_t)N * 128 * 4);
  float* h1b  = (float*)alloc((size_t)N * 128 * 4);
  unsigned short* h0s0 = (unsigned short*)alloc((size_t)125 * 8 * 2 * 512 * 2);
  unsigned short* h0s1 = (unsigned short*)alloc((size_t)125 * 8 * 2 * 512 * 2);
  unsigned short* h1s0 = (unsigned short*)alloc((size_t)125 * 8 * 2 * 512 * 2);
  unsigned short* h1s1 = (unsigned short*)alloc((size_t)125 * 8 * 2 * 512 * 2);
  unsigned short* w0f  = (unsigned short*)alloc((size_t)16 * 9 * 2 * 512 * 2);
  unsigned short* w1f  = (unsigned short*)alloc((size_t)16 * 16 * 2 * 512 * 2);
  float* biasP = (float*)alloc(1024 * 4);
  float* ssrc = (float*)alloc(N * 4);
  float* sdst = (float*)alloc(N * 4);
  float* uv   = (float*)alloc(272 * 4);
  float* part = (float*)alloc(4096 * 4);
  float* csum = (float*)alloc(128 * 4);

  unsigned short* h0s[2] = {h0s0, h0s1};
  unsigned short* h1s[2] = {h1s0, h1s1};

  hipLaunchKernelGGL(pack_w, dim3(288), dim3(256), 0, stream, Wih0, Whh0, 16, 9, w0f);
  hipLaunchKernelGGL(pack_w, dim3(512), dim3(256), 0, stream, Wih1, Whh1, 128, 16, w1f);
  hipLaunchKernelGGL(pack_bias, dim3(4), dim3(256), 0, stream, bih0, bhh0, bih1, bhh1, biasP);

  dim3 grid(63, 4, 2), blk(256);
  for (int s = 0; s <= TT; s++) {
    SArgs A0 = {}, A1 = {};
    A0.active = (s < TT) ? 1 : 0;
    if (A0.active) {
      int t = s;
      A0.W = w0f; A0.ncW = 9;
      A0.xf32 = x + (size_t)t * 16;
      A0.Bx = nullptr; A0.bxc = 0;
      A0.Bh = (t == 0) ? nullptr : h0s[(t + 1) & 1];
      A0.cin = (t == 0) ? nullptr : c0; A0.cout = c0;
      A0.hout = h0s[t & 1]; A0.hf32 = nullptr;
      A0.bias = biasP;
    }
    A1.active = (s >= 1) ? 1 : 0;
    if (A1.active) {
      int t = s - 1;
      A1.W = w1f; A1.ncW = 16;
      A1.xf32 = nullptr;
      A1.Bx = h0s[t & 1]; A1.bxc = 8;
      A1.Bh = (t == 0) ? nullptr : h1s[(t + 1) & 1];
      A1.cin = (t == 0) ? nullptr : c1; A1.cout = c1;
      A1.hout = h1s[t & 1]; A1.hf32 = h1a;
      A1.bias = biasP + 512;
    }
    hipLaunchKernelGGL(lstm_mfma, grid, blk, 0, stream, A0, A1);
  }

  hipLaunchKernelGGL(attn_prep, dim3(1), dim3(128), 0, stream, Wtr, btr, avec, uv);
  for (int r = 0; r < 2; r++) {
    const float* hid = r ? h1b : h1a;
    float* hnew = r ? h1a : h1b;
    hipLaunchKernelGGL(attn_scores, dim3(1000), dim3(256), 0, stream, hid, uv, ssrc, sdst, N);
    hipLaunchKernelGGL(colsum_part, dim3(32), dim3(128), 0, stream, hid, part, N);
    hipLaunchKernelGGL(colsum_fold, dim3(1), dim3(128), 0, stream, part, csum);
    hipLaunchKernelGGL(attn_row, dim3(N), dim3(128), 0, stream, adj, ssrc, sdst, hid, csum, hnew, N);
  }
  hipLaunchKernelGGL(head_kernel, dim3(125), dim3(256), 0, stream, h1a, Wfc, bfc, Wout, bout, out, N);
}